// Round 6
// baseline (55.837 us; speedup 1.0000x reference)
//
#include <hip/hip_runtime.h>
#include <math.h>

#define BB 8
#define LX 128
#define LY 512
#define DD 256

// ws layout (floats):
//   A    [B][LX][D]                          @ 0
//   Ct2  [B][D/4][LY][4]                     @ CT2_OFF
//   part [B][8][8][16][D]   (xg,yc,row)      @ PART_OFF   (8 MB)
//   pml  [B][8][8][16]      (l sums)         @ PML_OFF
#define A_ELEMS    (BB * LX * DD)                 // 262144
#define CT2_OFF    A_ELEMS
#define CT2_ELEMS  (BB * (DD / 4) * LY * 4)       // 1048576
#define PART_OFF   (CT2_OFF + CT2_ELEMS)          // 1310720
#define PART_ELEMS (BB * 8 * 8 * 16 * DD)         // 2097152
#define PML_OFF    (PART_OFF + PART_ELEMS)        // 3407872

// ---------------------------------------------------------------------------
// Kernel 1: fused GEMMs, 16x128 tiles, grid 640 (round-2 version, known good).
//   wgs 0..127   : A[r, cols] = x_row @ W1[:D] + b1
//   wgs 128..639 : Ct2[b][d/4][y][d%4] = y_row @ W1[D:]
// ---------------------------------------------------------------------------
__global__ __launch_bounds__(256) void gemm_kernel(
    const float* __restrict__ x, const float* __restrict__ y,
    const float* __restrict__ W1, const float* __restrict__ b1,
    float* __restrict__ ws)
{
    __shared__ float sA[32][20];    // [k][row], 16 rows padded
    __shared__ float sW[32][128];   // [k][col]

    const int g  = blockIdx.x;
    const int t  = threadIdx.x;
    const int tc = t & 31;          // cols col0 + 4tc .. +3
    const int tr = t >> 5;          // rows 2tr, 2tr+1

    const bool isA = (g < 128);
    const float* inp;
    const float* wbase;
    int row0, col0;
    if (isA) { col0 = (g & 1) * 128;  row0 = (g >> 1) * 16;  inp = x; wbase = W1; }
    else     { int h = g - 128; col0 = (h & 1) * 128; row0 = (h >> 1) * 16; inp = y; wbase = W1 + DD * DD; }

    float acc[2][4];
    #pragma unroll
    for (int i = 0; i < 2; ++i)
        #pragma unroll
        for (int j = 0; j < 4; ++j) acc[i][j] = 0.f;

    for (int k0 = 0; k0 < DD; k0 += 32) {
        __syncthreads();
        if (t < 128) {                       // stage 16x32 input block, transposed
            int row = t >> 3, kq = t & 7;
            const float4 v = *(const float4*)(inp + (size_t)(row0 + row) * DD + k0 + 4 * kq);
            sA[4*kq + 0][row] = v.x;
            sA[4*kq + 1][row] = v.y;
            sA[4*kq + 2][row] = v.z;
            sA[4*kq + 3][row] = v.w;
        }
        #pragma unroll
        for (int i = 0; i < 4; ++i) {        // stage 32x128 W block
            int flat = t + i * 256;          // float4 index over [32][32]
            int kk = flat >> 5, c4 = flat & 31;
            *(float4*)&sW[kk][4*c4] = *(const float4*)(wbase + (size_t)(k0 + kk) * DD + col0 + 4 * c4);
        }
        __syncthreads();
        #pragma unroll
        for (int k = 0; k < 32; ++k) {
            const float a0 = sA[k][2*tr], a1 = sA[k][2*tr + 1];
            const float4 w4 = *(const float4*)&sW[k][4*tc];
            acc[0][0] = fmaf(a0, w4.x, acc[0][0]);
            acc[0][1] = fmaf(a0, w4.y, acc[0][1]);
            acc[0][2] = fmaf(a0, w4.z, acc[0][2]);
            acc[0][3] = fmaf(a0, w4.w, acc[0][3]);
            acc[1][0] = fmaf(a1, w4.x, acc[1][0]);
            acc[1][1] = fmaf(a1, w4.y, acc[1][1]);
            acc[1][2] = fmaf(a1, w4.z, acc[1][2]);
            acc[1][3] = fmaf(a1, w4.w, acc[1][3]);
        }
    }

    if (isA) {
        const float4 bv = *(const float4*)(b1 + col0 + 4 * tc);
        #pragma unroll
        for (int i = 0; i < 2; ++i) {
            const int r = row0 + 2 * tr + i;
            float4 o;
            o.x = acc[i][0] + bv.x; o.y = acc[i][1] + bv.y;
            o.z = acc[i][2] + bv.z; o.w = acc[i][3] + bv.w;
            *(float4*)(ws + (size_t)r * DD + col0 + 4 * tc) = o;
        }
    } else {
        const int dq = (col0 >> 2) + tc;
        #pragma unroll
        for (int i = 0; i < 2; ++i) {
            const int ry = row0 + 2 * tr + i;           // [0,4096)
            const int bb = ry >> 9, yy = ry & 511;
            float4 o = {acc[i][0], acc[i][1], acc[i][2], acc[i][3]};
            *(float4*)(ws + CT2_OFF + (((size_t)(bb * 64 + dq) * 512 + yy) << 2)) = o;
        }
    }
}

// ---------------------------------------------------------------------------
// Kernel 2: partial attention. LDS-free, barrier-free, no-max exp.
// grid 512 = (b = bid&7) x (xg: 16-row group, 8 of them) x (yc: 64-y chunk, 8).
// 256 threads = 4 waves; wave w owns rows xg*16 + 4w .. +3 (A,W2 wave-uniform
// -> scalar loads). lane = y within chunk. Phase-2 broadcast via v_readlane.
// 4 rows/wave halves Ct2+y L2 traffic vs 2 rows/wave (512 -> 260 MB).
// ---------------------------------------------------------------------------
__global__ __launch_bounds__(256, 2) void score_kernel(
    const float* __restrict__ yin, const int* __restrict__ ymask,
    const float* __restrict__ W2, const float* __restrict__ b2,
    const float* __restrict__ Ain, const float* __restrict__ Ct,
    float* __restrict__ part, float* __restrict__ pml)
{
    const int t    = threadIdx.x;
    const int lane = t & 63;
    const int w    = __builtin_amdgcn_readfirstlane(t >> 6);  // wave id, SGPR
    const int b    = blockIdx.x & 7;
    const int r    = blockIdx.x >> 3;    // [0,64)
    const int xg   = r & 7;              // 16-row group
    const int yc   = r >> 3;             // [0,8) 64-y chunk
    const int y    = yc * 64 + lane;
    const int row0 = xg * 16 + w * 4;    // this wave's first row in [0,128)

    const bool msk = ymask[(size_t)b * LY + y] != 0;

    const float4* A4  = (const float4*)(Ain + ((size_t)b * LX + row0) * DD);  // rows: +64 f4
    const float4* W24 = (const float4*)W2;
    const float4* ct  = (const float4*)Ct + ((size_t)b * 64) * 512 + y;
    const float b2v = b2[0];

    float s0a=0.f,s0b=0.f,s1a=0.f,s1b=0.f,s2a=0.f,s2b=0.f,s3a=0.f,s3b=0.f;

    #pragma unroll 8
    for (int dq = 0; dq < 64; ++dq) {
        const float4 c  = ct[(size_t)dq * 512];   // per-lane y, coalesced 1KB/wave
        const float4 w4 = W24[dq];                // wave-uniform -> s_load
        const float4 a0 = A4[dq];                 // wave-uniform -> s_load
        const float4 a1 = A4[dq + 64];
        const float4 a2 = A4[dq + 128];
        const float4 a3 = A4[dq + 192];
        s0a = fmaf(fmaxf(a0.x + c.x, 0.f), w4.x, s0a);
        s0b = fmaf(fmaxf(a0.y + c.y, 0.f), w4.y, s0b);
        s0a = fmaf(fmaxf(a0.z + c.z, 0.f), w4.z, s0a);
        s0b = fmaf(fmaxf(a0.w + c.w, 0.f), w4.w, s0b);
        s1a = fmaf(fmaxf(a1.x + c.x, 0.f), w4.x, s1a);
        s1b = fmaf(fmaxf(a1.y + c.y, 0.f), w4.y, s1b);
        s1a = fmaf(fmaxf(a1.z + c.z, 0.f), w4.z, s1a);
        s1b = fmaf(fmaxf(a1.w + c.w, 0.f), w4.w, s1b);
        s2a = fmaf(fmaxf(a2.x + c.x, 0.f), w4.x, s2a);
        s2b = fmaf(fmaxf(a2.y + c.y, 0.f), w4.y, s2b);
        s2a = fmaf(fmaxf(a2.z + c.z, 0.f), w4.z, s2a);
        s2b = fmaf(fmaxf(a2.w + c.w, 0.f), w4.w, s2b);
        s3a = fmaf(fmaxf(a3.x + c.x, 0.f), w4.x, s3a);
        s3b = fmaf(fmaxf(a3.y + c.y, 0.f), w4.y, s3b);
        s3a = fmaf(fmaxf(a3.z + c.z, 0.f), w4.z, s3a);
        s3b = fmaf(fmaxf(a3.w + c.w, 0.f), w4.w, s3b);
    }

    const float p0 = msk ? 0.f : __expf(s0a + s0b + b2v);
    const float p1 = msk ? 0.f : __expf(s1a + s1b + b2v);
    const float p2 = msk ? 0.f : __expf(s2a + s2b + b2v);
    const float p3 = msk ? 0.f : __expf(s3a + s3b + b2v);

    // row l-sums (off the critical path)
    float l0 = p0, l1 = p1, l2 = p2, l3 = p3;
    #pragma unroll
    for (int off = 32; off; off >>= 1) {
        l0 += __shfl_xor(l0, off);
        l1 += __shfl_xor(l1, off);
        l2 += __shfl_xor(l2, off);
        l3 += __shfl_xor(l3, off);
    }

    // ---- phase 2: partial context; p broadcast via v_readlane (VALU pipe)
    const int pi0 = __float_as_int(p0);
    const int pi1 = __float_as_int(p1);
    const int pi2 = __float_as_int(p2);
    const int pi3 = __float_as_int(p3);
    float4 acc0 = {0,0,0,0}, acc1 = {0,0,0,0}, acc2 = {0,0,0,0}, acc3 = {0,0,0,0};
    const float4* yb4 = (const float4*)(yin + ((size_t)b * LY + yc * 64) * DD) + lane;

    #pragma unroll 8
    for (int yy = 0; yy < 64; ++yy) {
        const float4 v = yb4[(size_t)yy * 64];    // lane owns d-quad 4*lane..+3
        const float q0 = __int_as_float(__builtin_amdgcn_readlane(pi0, yy));
        const float q1 = __int_as_float(__builtin_amdgcn_readlane(pi1, yy));
        const float q2 = __int_as_float(__builtin_amdgcn_readlane(pi2, yy));
        const float q3 = __int_as_float(__builtin_amdgcn_readlane(pi3, yy));
        acc0.x = fmaf(q0, v.x, acc0.x); acc0.y = fmaf(q0, v.y, acc0.y);
        acc0.z = fmaf(q0, v.z, acc0.z); acc0.w = fmaf(q0, v.w, acc0.w);
        acc1.x = fmaf(q1, v.x, acc1.x); acc1.y = fmaf(q1, v.y, acc1.y);
        acc1.z = fmaf(q1, v.z, acc1.z); acc1.w = fmaf(q1, v.w, acc1.w);
        acc2.x = fmaf(q2, v.x, acc2.x); acc2.y = fmaf(q2, v.y, acc2.y);
        acc2.z = fmaf(q2, v.z, acc2.z); acc2.w = fmaf(q2, v.w, acc2.w);
        acc3.x = fmaf(q3, v.x, acc3.x); acc3.y = fmaf(q3, v.y, acc3.y);
        acc3.z = fmaf(q3, v.z, acc3.z); acc3.w = fmaf(q3, v.w, acc3.w);
    }

    // part rows for this wave are consecutive: local rows 4w..4w+3
    float* pb = part + (((size_t)(b * 8 + xg) * 8 + yc) * 16 + 4 * w) * DD;
    *(float4*)(pb + 0 * DD + 4 * lane) = acc0;
    *(float4*)(pb + 1 * DD + 4 * lane) = acc1;
    *(float4*)(pb + 2 * DD + 4 * lane) = acc2;
    *(float4*)(pb + 3 * DD + 4 * lane) = acc3;
    if (lane == 0) {
        float* ml = pml + ((size_t)(b * 8 + xg) * 8 + yc) * 16 + 4 * w;
        ml[0] = l0; ml[1] = l1; ml[2] = l2; ml[3] = l3;
    }
}

// ---------------------------------------------------------------------------
// Kernel 3: linear combine of the 8 y-chunk partials per (b, x) row. grid 1024.
// ---------------------------------------------------------------------------
__global__ __launch_bounds__(256) void combine_kernel(
    const float* __restrict__ part, const float* __restrict__ pml,
    float* __restrict__ out)
{
    const int t = threadIdx.x;
    const int b = blockIdx.x & 7;
    const int x = blockIdx.x >> 3;      // [0,128)
    const int xg = x >> 4, xi = x & 15;

    float L = 0.f;
    #pragma unroll
    for (int c = 0; c < 8; ++c)
        L += pml[((size_t)(b * 8 + xg) * 8 + c) * 16 + xi];

    float acc = 0.f;
    #pragma unroll
    for (int c = 0; c < 8; ++c)
        acc += part[(((size_t)(b * 8 + xg) * 8 + c) * 16 + xi) * DD + t];

    out[((size_t)(b * LX + x)) * DD + t] = acc / L;
}

// ---------------------------------------------------------------------------
extern "C" void kernel_launch(void* const* d_in, const int* in_sizes, int n_in,
                              void* d_out, int out_size, void* d_ws, size_t ws_size,
                              hipStream_t stream) {
    const float* x     = (const float*)d_in[0];
    const float* y     = (const float*)d_in[1];
    const int*   ymask = (const int*)  d_in[2];
    const float* W1    = (const float*)d_in[3];
    const float* b1    = (const float*)d_in[4];
    const float* W2    = (const float*)d_in[5];
    const float* b2    = (const float*)d_in[6];
    float* ws  = (float*)d_ws;
    float* out = (float*)d_out;

    hipLaunchKernelGGL(gemm_kernel, dim3(640), dim3(256), 0, stream, x, y, W1, b1, ws);
    hipLaunchKernelGGL(score_kernel, dim3(512), dim3(256), 0, stream,
                       y, ymask, W2, b2, ws, ws + CT2_OFF, ws + PART_OFF, ws + PML_OFF);
    hipLaunchKernelGGL(combine_kernel, dim3(1024), dim3(256), 0, stream,
                       ws + PART_OFF, ws + PML_OFF, out);
}

// Round 7
// 50.410 us; speedup vs baseline: 1.1077x; 1.1077x over previous
//
#include <hip/hip_runtime.h>
#include <math.h>

#define BB 8
#define LX 128
#define LY 512
#define DD 256

typedef _Float16 h2t __attribute__((ext_vector_type(2)));

static __device__ __forceinline__ h2t u2h(unsigned int u) {
    h2t r; __builtin_memcpy(&r, &u, 4); return r;
}
static __device__ __forceinline__ unsigned int pk16(float a, float b) {
    h2t h; h.x = (_Float16)a; h.y = (_Float16)b;
    unsigned int u; __builtin_memcpy(&u, &h, 4); return u;
}

#if defined(__has_builtin) && __has_builtin(__builtin_amdgcn_fdot2)
#define DOT2(a, b, c) __builtin_amdgcn_fdot2((a), (b), (c), false)
#else
#define DOT2(a, b, c) fmaf((float)(a).x, (float)(b).x, fmaf((float)(a).y, (float)(b).y, (c)))
#endif

// ws layout (floats):
//   A16  [B*LX][32][2] uint2 (f16 pairs; slot dqi, sel=dq>>5)   @ 0        (131072)
//   CT16 [B][64][LY]   uint2 (4 f16 per y per d-quad)           @ 131072   (524288)
//   W16  [32][2]       uint2                                    @ 655360   (128)
//   part [B][16][4][4][8][D] f32                                @ 655488   (4194304)
//   pml  [B][16][4][4][8]    f32                                @ 4849792  (16384)
#define A16_OFF  0
#define CT16_OFF 131072
#define W16_OFF  655360
#define PART_OFF 655488
#define PML_OFF  4849792

// ---------------------------------------------------------------------------
// Kernel 1: fused GEMMs (fp32 math, known good), f16-packed outputs.
//   wgs 0..127   : A16[row] = f16(x_row @ W1[:D] + b1)
//   wgs 128..639 : CT16[b][dq][y] = f16(y_row @ W1[D:])
// ---------------------------------------------------------------------------
__global__ __launch_bounds__(256) void gemm_kernel(
    const float* __restrict__ x, const float* __restrict__ y,
    const float* __restrict__ W1, const float* __restrict__ b1,
    const float* __restrict__ W2, float* __restrict__ ws)
{
    __shared__ float sA[32][20];
    __shared__ float sW[32][128];

    const int g  = blockIdx.x;
    const int t  = threadIdx.x;
    const int tc = t & 31;
    const int tr = t >> 5;

    const bool isA = (g < 128);
    const float* inp;
    const float* wbase;
    int row0, col0;
    if (isA) { col0 = (g & 1) * 128;  row0 = (g >> 1) * 16;  inp = x; wbase = W1; }
    else     { int h = g - 128; col0 = (h & 1) * 128; row0 = (h >> 1) * 16; inp = y; wbase = W1 + DD * DD; }

    float acc[2][4];
    #pragma unroll
    for (int i = 0; i < 2; ++i)
        #pragma unroll
        for (int j = 0; j < 4; ++j) acc[i][j] = 0.f;

    for (int k0 = 0; k0 < DD; k0 += 32) {
        __syncthreads();
        if (t < 128) {
            int row = t >> 3, kq = t & 7;
            const float4 v = *(const float4*)(inp + (size_t)(row0 + row) * DD + k0 + 4 * kq);
            sA[4*kq + 0][row] = v.x;
            sA[4*kq + 1][row] = v.y;
            sA[4*kq + 2][row] = v.z;
            sA[4*kq + 3][row] = v.w;
        }
        #pragma unroll
        for (int i = 0; i < 4; ++i) {
            int flat = t + i * 256;
            int kk = flat >> 5, c4 = flat & 31;
            *(float4*)&sW[kk][4*c4] = *(const float4*)(wbase + (size_t)(k0 + kk) * DD + col0 + 4 * c4);
        }
        __syncthreads();
        #pragma unroll
        for (int k = 0; k < 32; ++k) {
            const float a0 = sA[k][2*tr], a1 = sA[k][2*tr + 1];
            const float4 w4 = *(const float4*)&sW[k][4*tc];
            acc[0][0] = fmaf(a0, w4.x, acc[0][0]);
            acc[0][1] = fmaf(a0, w4.y, acc[0][1]);
            acc[0][2] = fmaf(a0, w4.z, acc[0][2]);
            acc[0][3] = fmaf(a0, w4.w, acc[0][3]);
            acc[1][0] = fmaf(a1, w4.x, acc[1][0]);
            acc[1][1] = fmaf(a1, w4.y, acc[1][1]);
            acc[1][2] = fmaf(a1, w4.z, acc[1][2]);
            acc[1][3] = fmaf(a1, w4.w, acc[1][3]);
        }
    }

    const int dq = (col0 >> 2) + tc;                 // d-quad [0,64)
    if (isA) {
        uint2* A16u2 = (uint2*)(ws + A16_OFF);
        const float4 bv = *(const float4*)(b1 + col0 + 4 * tc);
        #pragma unroll
        for (int i = 0; i < 2; ++i) {
            const int r = row0 + 2 * tr + i;         // global x row [0,1024)
            uint2 st;
            st.x = pk16(acc[i][0] + bv.x, acc[i][1] + bv.y);
            st.y = pk16(acc[i][2] + bv.z, acc[i][3] + bv.w);
            A16u2[((size_t)r * 32 + (dq & 31)) * 2 + (dq >> 5)] = st;
        }
        if (g == 0 && t < 64) {                      // build W16 once
            uint2* W16u2 = (uint2*)(ws + W16_OFF);
            const float4 wv = *(const float4*)(W2 + 4 * t);
            uint2 st;
            st.x = pk16(wv.x, wv.y);
            st.y = pk16(wv.z, wv.w);
            W16u2[((t & 31)) * 2 + (t >> 5)] = st;
        }
    } else {
        uint2* Ct16u2 = (uint2*)(ws + CT16_OFF);
        #pragma unroll
        for (int i = 0; i < 2; ++i) {
            const int ry = row0 + 2 * tr + i;        // [0,4096)
            const int bb = ry >> 9, yy = ry & 511;
            uint2 st;
            st.x = pk16(acc[i][0], acc[i][1]);
            st.y = pk16(acc[i][2], acc[i][3]);
            Ct16u2[((size_t)(bb * 64 + dq)) * 512 + yy] = st;
        }
    }
}

// ---------------------------------------------------------------------------
// Kernel 2: partial attention, f16 phase 1, zero LDS / zero barriers.
// grid 512 = (b = bid&7) x (xg: 8-row group, 16) x (yc: 128-y chunk, 4).
// 4 waves; wave w owns y [yc*128+32w, +32). Lane = (ylo 0..31) x (d-half).
// All 8 rows' A and W2 are wave-uniform scalar loads; d-half picked by
// cndmask. Scores accumulate in f32 via v_dot2_f32_f16.
// ---------------------------------------------------------------------------
__global__ __launch_bounds__(256) void score_kernel(
    const float* __restrict__ yin, const int* __restrict__ ymask,
    const float* __restrict__ b2,
    const uint4* __restrict__ A16, const uint2* __restrict__ Ct,
    const uint4* __restrict__ W16,
    float* __restrict__ part, float* __restrict__ pml)
{
    const int t    = threadIdx.x;
    const int lane = t & 63;
    const int w    = __builtin_amdgcn_readfirstlane(t >> 6);
    const int b    = blockIdx.x & 7;
    const int r2   = blockIdx.x >> 3;    // [0,64)
    const int xg   = r2 & 15;            // 8-row group
    const int yc   = r2 >> 4;            // [0,4) 128-y chunk
    const int ylo  = lane & 31;
    const bool hi  = (lane >> 5) != 0;   // d-half
    const int y    = yc * 128 + w * 32 + ylo;
    const int grow0 = b * LX + xg * 8;   // global x-row base (8 rows)

    const uint2* ctp = Ct + ((size_t)(b * 64 + (hi ? 32 : 0))) * 512 + y;
    const uint4* A8  = A16 + (size_t)grow0 * 32;
    const float  b2v = b2[0];

    h2t zz; zz.x = (_Float16)0.f; zz.y = (_Float16)0.f;
    float sA[8], sB[8];
    #pragma unroll
    for (int r = 0; r < 8; ++r) { sA[r] = 0.f; sB[r] = 0.f; }

    #pragma unroll 2
    for (int dqi = 0; dqi < 32; ++dqi) {
        const uint2 cu = ctp[(size_t)dqi * 512];     // 4 f16 c-values (this d-half)
        const h2t c0 = u2h(cu.x), c1 = u2h(cu.y);
        const uint4 wv = W16[dqi];
        const h2t w0 = u2h(hi ? wv.z : wv.x);
        const h2t w1 = u2h(hi ? wv.w : wv.y);
        #pragma unroll
        for (int r = 0; r < 8; ++r) {
            const uint4 av = A8[r * 32 + dqi];       // uniform -> s_load_dwordx4
            const h2t a0 = u2h(hi ? av.z : av.x);
            const h2t a1 = u2h(hi ? av.w : av.y);
            const h2t h0 = __builtin_elementwise_max(a0 + c0, zz);
            const h2t h1 = __builtin_elementwise_max(a1 + c1, zz);
            sA[r] = DOT2(h0, w0, sA[r]);
            sB[r] = DOT2(h1, w1, sB[r]);
        }
    }

    const bool msk = ymask[(size_t)b * LY + y] != 0;
    float p[8]; int pi[8]; float l[8];
    #pragma unroll
    for (int r = 0; r < 8; ++r) {
        float s = sA[r] + sB[r];
        s += __shfl_xor(s, 32);                      // merge d-halves
        p[r] = msk ? 0.f : __expf(s + b2v);
        pi[r] = __float_as_int(p[r]);
        float lv = p[r];
        #pragma unroll
        for (int off = 16; off; off >>= 1) lv += __shfl_xor(lv, off);
        l[r] = lv;
    }

    // ---- phase 2: partial context over this wave's 32 y-rows -------------
    float4 acc[8];
    #pragma unroll
    for (int r = 0; r < 8; ++r) acc[r] = make_float4(0.f, 0.f, 0.f, 0.f);

    const float4* yb = (const float4*)yin + ((size_t)(b * LY + yc * 128 + w * 32)) * 64 + lane;
    #pragma unroll 4
    for (int yy = 0; yy < 32; ++yy) {
        const float4 v = yb[(size_t)yy * 64];        // lane owns d-quad 4*lane..+3
        #pragma unroll
        for (int r = 0; r < 8; ++r) {
            const float q = __int_as_float(__builtin_amdgcn_readlane(pi[r], yy));
            acc[r].x = fmaf(q, v.x, acc[r].x);
            acc[r].y = fmaf(q, v.y, acc[r].y);
            acc[r].z = fmaf(q, v.z, acc[r].z);
            acc[r].w = fmaf(q, v.w, acc[r].w);
        }
    }

    const size_t pw = (((size_t)(b * 16 + xg) * 4 + yc) * 4 + w);
    float* pb = part + pw * 8 * DD;
    #pragma unroll
    for (int r = 0; r < 8; ++r)
        *(float4*)(pb + (size_t)r * DD + 4 * lane) = acc[r];
    if (lane == 0) {
        #pragma unroll
        for (int r = 0; r < 8; ++r) pml[pw * 8 + r] = l[r];
    }
}

// ---------------------------------------------------------------------------
// Kernel 3: combine 16 (yc,w) partials per (b, x) row. grid 1024.
// ---------------------------------------------------------------------------
__global__ __launch_bounds__(256) void combine_kernel(
    const float* __restrict__ part, const float* __restrict__ pml,
    float* __restrict__ out)
{
    const int t = threadIdx.x;
    const int b = blockIdx.x & 7;
    const int x = blockIdx.x >> 3;      // [0,128)
    const int xg = x >> 3, xi = x & 7;

    float L = 0.f;
    float acc = 0.f;
    #pragma unroll
    for (int c = 0; c < 16; ++c) {
        const size_t idx = (((size_t)(b * 16 + xg) * 4 + (c >> 2)) * 4 + (c & 3)) * 8 + xi;
        L   += pml[idx];
        acc += part[idx * DD + t];
    }
    out[((size_t)(b * LX + x)) * DD + t] = acc / L;
}

// ---------------------------------------------------------------------------
extern "C" void kernel_launch(void* const* d_in, const int* in_sizes, int n_in,
                              void* d_out, int out_size, void* d_ws, size_t ws_size,
                              hipStream_t stream) {
    const float* x     = (const float*)d_in[0];
    const float* y     = (const float*)d_in[1];
    const int*   ymask = (const int*)  d_in[2];
    const float* W1    = (const float*)d_in[3];
    const float* b1    = (const float*)d_in[4];
    const float* W2    = (const float*)d_in[5];
    const float* b2    = (const float*)d_in[6];
    float* ws  = (float*)d_ws;
    float* out = (float*)d_out;

    hipLaunchKernelGGL(gemm_kernel, dim3(640), dim3(256), 0, stream, x, y, W1, b1, W2, ws);
    hipLaunchKernelGGL(score_kernel, dim3(512), dim3(256), 0, stream,
                       y, ymask, b2,
                       (const uint4*)(ws + A16_OFF), (const uint2*)(ws + CT16_OFF),
                       (const uint4*)(ws + W16_OFF),
                       ws + PART_OFF, ws + PML_OFF);
    hipLaunchKernelGGL(combine_kernel, dim3(1024), dim3(256), 0, stream,
                       ws + PART_OFF, ws + PML_OFF, out);
}

// Round 8
// 46.083 us; speedup vs baseline: 1.2116x; 1.0939x over previous
//
#include <hip/hip_runtime.h>
#include <math.h>

#define BB 8
#define LX 128
#define LY 512
#define DD 256

typedef _Float16 h2t __attribute__((ext_vector_type(2)));

static __device__ __forceinline__ h2t u2h(unsigned int u) {
    h2t r; __builtin_memcpy(&r, &u, 4); return r;
}
static __device__ __forceinline__ unsigned int pk16(float a, float b) {
    h2t h; h.x = (_Float16)a; h.y = (_Float16)b;
    unsigned int u; __builtin_memcpy(&u, &h, 4); return u;
}
static __device__ __forceinline__ h2t rlh(unsigned int v, int l) {
    return u2h((unsigned int)__builtin_amdgcn_readlane((int)v, l));
}

#if defined(__has_builtin) && __has_builtin(__builtin_amdgcn_fdot2)
#define DOT2(a, b, c) __builtin_amdgcn_fdot2((a), (b), (c), false)
#else
#define DOT2(a, b, c) fmaf((float)(a).x, (float)(b).x, fmaf((float)(a).y, (float)(b).y, (c)))
#endif

// ws layout (floats):
//   A16  [B*LX][64] uint2  (row-major d-quads, f16 pairs)  @ 0        (131072 f)
//   CT16 [B][64][LY] uint2 (4 f16 per y per d-quad)        @ 131072   (524288 f)
//   W16  [64] uint2                                        @ 655360   (128 f)
#define A16_OFF  0
#define CT16_OFF 131072
#define W16_OFF  655360

// ---------------------------------------------------------------------------
// Kernel 1: fused GEMMs (fp32 math), f16-packed outputs.
//   wgs 0..127   : A16[row][dq] = f16(x_row @ W1[:D] + b1)
//   wgs 128..639 : CT16[b][dq][y] = f16(y_row @ W1[D:])
// ---------------------------------------------------------------------------
__global__ __launch_bounds__(256) void gemm_kernel(
    const float* __restrict__ x, const float* __restrict__ y,
    const float* __restrict__ W1, const float* __restrict__ b1,
    const float* __restrict__ W2, float* __restrict__ ws)
{
    __shared__ float sA[32][20];
    __shared__ float sW[32][128];

    const int g  = blockIdx.x;
    const int t  = threadIdx.x;
    const int tc = t & 31;
    const int tr = t >> 5;

    const bool isA = (g < 128);
    const float* inp;
    const float* wbase;
    int row0, col0;
    if (isA) { col0 = (g & 1) * 128;  row0 = (g >> 1) * 16;  inp = x; wbase = W1; }
    else     { int h = g - 128; col0 = (h & 1) * 128; row0 = (h >> 1) * 16; inp = y; wbase = W1 + DD * DD; }

    float acc[2][4];
    #pragma unroll
    for (int i = 0; i < 2; ++i)
        #pragma unroll
        for (int j = 0; j < 4; ++j) acc[i][j] = 0.f;

    for (int k0 = 0; k0 < DD; k0 += 32) {
        __syncthreads();
        if (t < 128) {
            int row = t >> 3, kq = t & 7;
            const float4 v = *(const float4*)(inp + (size_t)(row0 + row) * DD + k0 + 4 * kq);
            sA[4*kq + 0][row] = v.x;
            sA[4*kq + 1][row] = v.y;
            sA[4*kq + 2][row] = v.z;
            sA[4*kq + 3][row] = v.w;
        }
        #pragma unroll
        for (int i = 0; i < 4; ++i) {
            int flat = t + i * 256;
            int kk = flat >> 5, c4 = flat & 31;
            *(float4*)&sW[kk][4*c4] = *(const float4*)(wbase + (size_t)(k0 + kk) * DD + col0 + 4 * c4);
        }
        __syncthreads();
        #pragma unroll
        for (int k = 0; k < 32; ++k) {
            const float a0 = sA[k][2*tr], a1 = sA[k][2*tr + 1];
            const float4 w4 = *(const float4*)&sW[k][4*tc];
            acc[0][0] = fmaf(a0, w4.x, acc[0][0]);
            acc[0][1] = fmaf(a0, w4.y, acc[0][1]);
            acc[0][2] = fmaf(a0, w4.z, acc[0][2]);
            acc[0][3] = fmaf(a0, w4.w, acc[0][3]);
            acc[1][0] = fmaf(a1, w4.x, acc[1][0]);
            acc[1][1] = fmaf(a1, w4.y, acc[1][1]);
            acc[1][2] = fmaf(a1, w4.z, acc[1][2]);
            acc[1][3] = fmaf(a1, w4.w, acc[1][3]);
        }
    }

    const int dq = (col0 >> 2) + tc;                 // d-quad [0,64)
    if (isA) {
        uint2* A16u2 = (uint2*)(ws + A16_OFF);
        const float4 bv = *(const float4*)(b1 + col0 + 4 * tc);
        #pragma unroll
        for (int i = 0; i < 2; ++i) {
            const int r = row0 + 2 * tr + i;         // global x row [0,1024)
            uint2 st;
            st.x = pk16(acc[i][0] + bv.x, acc[i][1] + bv.y);
            st.y = pk16(acc[i][2] + bv.z, acc[i][3] + bv.w);
            A16u2[(size_t)r * 64 + dq] = st;
        }
        if (g == 0 && t < 64) {                      // build W16 once
            uint2* W16u2 = (uint2*)(ws + W16_OFF);
            const float4 wv = *(const float4*)(W2 + 4 * t);
            uint2 st;
            st.x = pk16(wv.x, wv.y);
            st.y = pk16(wv.z, wv.w);
            W16u2[t] = st;
        }
    } else {
        uint2* Ct16u2 = (uint2*)(ws + CT16_OFF);
        #pragma unroll
        for (int i = 0; i < 2; ++i) {
            const int ry = row0 + 2 * tr + i;        // [0,4096)
            const int bb = ry >> 9, yy = ry & 511;
            uint2 st;
            st.x = pk16(acc[i][0], acc[i][1]);
            st.y = pk16(acc[i][2], acc[i][3]);
            Ct16u2[((size_t)(bb * 64 + dq)) * 512 + yy] = st;
        }
    }
}

// ---------------------------------------------------------------------------
// Kernel 2: fused score+softmax+context+normalize.
// grid 256 = (b = bid&7) x (xg: 4-row group, 32 of them). 512 threads (8 waves).
// Phase 1: wave w owns y = w*64+lane (all 512 y covered). A rows + W2 live in
//   VGPRs, broadcast per-dq via v_readlane (SGPR lane index) -> the only
//   memory op in the loop is the coalesced ct uint2 load. f16 math, f32 acc.
// Phase 2: thread (d = t&255, xh = t>>8) accumulates 2 rows over all 512 y
//   (broadcast ds_read_b64 of p + coalesced Y load), writes out = acc/L.
// ---------------------------------------------------------------------------
__global__ __launch_bounds__(512) void fused_kernel(
    const float* __restrict__ yin, const int* __restrict__ ymask,
    const float* __restrict__ b2,
    const uint2* __restrict__ A16, const uint2* __restrict__ Ct,
    const uint2* __restrict__ W16,
    float* __restrict__ out)
{
    __shared__ __align__(16) float pl[LY][4];   // p values, 8 KB
    __shared__ __align__(16) float4 Lp[8];      // per-wave l partial (4 rows)

    const int t    = threadIdx.x;
    const int lane = t & 63;
    const int w    = __builtin_amdgcn_readfirstlane(t >> 6);  // wave id 0..7
    const int b    = blockIdx.x & 7;
    const int xg   = blockIdx.x >> 3;            // [0,32), rows xg*4..+3
    const int y    = w * 64 + lane;              // [0,512)

    // ---- distribute A rows + W2 into VGPRs (lane = d-quad) ---------------
    const uint2* Ab = A16 + ((size_t)(b * LX + xg * 4)) * 64;
    uint2 av0 = Ab[lane];
    uint2 av1 = Ab[64 + lane];
    uint2 av2 = Ab[128 + lane];
    uint2 av3 = Ab[192 + lane];
    const uint2 wv = W16[lane];

    const uint2* ctb = Ct + ((size_t)b * 64) * 512 + y;
    const float  b2v = b2[0];
    const bool   msk = ymask[(size_t)b * LY + y] != 0;

    float s0 = 0.f, s1 = 0.f, s2 = 0.f, s3 = 0.f;

    #pragma unroll 4
    for (int dq = 0; dq < 64; ++dq) {
        const uint2 cu = ctb[(size_t)dq * 512];          // coalesced, L2-hot
        const h2t c0 = u2h(cu.x), c1 = u2h(cu.y);
        const h2t w0 = rlh(wv.x, dq), w1 = rlh(wv.y, dq);
        h2t zz; zz.x = (_Float16)0.f; zz.y = (_Float16)0.f;
        {
            const h2t a0 = rlh(av0.x, dq), a1 = rlh(av0.y, dq);
            const h2t h0 = __builtin_elementwise_max(a0 + c0, zz);
            const h2t h1 = __builtin_elementwise_max(a1 + c1, zz);
            s0 = DOT2(h0, w0, s0); s0 = DOT2(h1, w1, s0);
        }
        {
            const h2t a0 = rlh(av1.x, dq), a1 = rlh(av1.y, dq);
            const h2t h0 = __builtin_elementwise_max(a0 + c0, zz);
            const h2t h1 = __builtin_elementwise_max(a1 + c1, zz);
            s1 = DOT2(h0, w0, s1); s1 = DOT2(h1, w1, s1);
        }
        {
            const h2t a0 = rlh(av2.x, dq), a1 = rlh(av2.y, dq);
            const h2t h0 = __builtin_elementwise_max(a0 + c0, zz);
            const h2t h1 = __builtin_elementwise_max(a1 + c1, zz);
            s2 = DOT2(h0, w0, s2); s2 = DOT2(h1, w1, s2);
        }
        {
            const h2t a0 = rlh(av3.x, dq), a1 = rlh(av3.y, dq);
            const h2t h0 = __builtin_elementwise_max(a0 + c0, zz);
            const h2t h1 = __builtin_elementwise_max(a1 + c1, zz);
            s3 = DOT2(h0, w0, s3); s3 = DOT2(h1, w1, s3);
        }
    }

    const float p0 = msk ? 0.f : __expf(s0 + b2v);
    const float p1 = msk ? 0.f : __expf(s1 + b2v);
    const float p2 = msk ? 0.f : __expf(s2 + b2v);
    const float p3 = msk ? 0.f : __expf(s3 + b2v);

    float l0 = p0, l1 = p1, l2 = p2, l3 = p3;
    #pragma unroll
    for (int off = 32; off; off >>= 1) {
        l0 += __shfl_xor(l0, off);
        l1 += __shfl_xor(l1, off);
        l2 += __shfl_xor(l2, off);
        l3 += __shfl_xor(l3, off);
    }

    *(float4*)&pl[y][0] = make_float4(p0, p1, p2, p3);
    if (lane == 0) Lp[w] = make_float4(l0, l1, l2, l3);
    __syncthreads();

    // ---- phase 2: contexts for 2 rows per thread -------------------------
    const int d  = t & 255;
    const int xh = t >> 8;                       // 0/1 -> rows 2xh, 2xh+1
    float L0 = 0.f, L1 = 0.f;
    #pragma unroll
    for (int ww = 0; ww < 8; ++ww) {
        const float4 lv = Lp[ww];
        L0 += xh ? lv.z : lv.x;
        L1 += xh ? lv.w : lv.y;
    }

    float a0 = 0.f, a1 = 0.f;
    const float* Yb = yin + (size_t)b * LY * DD + d;
    #pragma unroll 8
    for (int yy = 0; yy < LY; ++yy) {
        const float v = Yb[(size_t)yy * DD];
        const float2 pp = *(const float2*)&pl[yy][2 * xh];   // LDS broadcast
        a0 = fmaf(pp.x, v, a0);
        a1 = fmaf(pp.y, v, a1);
    }

    const size_t row = (size_t)(b * LX + xg * 4 + 2 * xh);
    out[row * DD + d]       = a0 / L0;
    out[(row + 1) * DD + d] = a1 / L1;
}

// ---------------------------------------------------------------------------
extern "C" void kernel_launch(void* const* d_in, const int* in_sizes, int n_in,
                              void* d_out, int out_size, void* d_ws, size_t ws_size,
                              hipStream_t stream) {
    const float* x     = (const float*)d_in[0];
    const float* y     = (const float*)d_in[1];
    const int*   ymask = (const int*)  d_in[2];
    const float* W1    = (const float*)d_in[3];
    const float* b1    = (const float*)d_in[4];
    const float* W2    = (const float*)d_in[5];
    const float* b2    = (const float*)d_in[6];
    float* ws  = (float*)d_ws;
    float* out = (float*)d_out;

    hipLaunchKernelGGL(gemm_kernel, dim3(640), dim3(256), 0, stream, x, y, W1, b1, W2, ws);
    hipLaunchKernelGGL(fused_kernel, dim3(256), dim3(512), 0, stream,
                       y, ymask, b2,
                       (const uint2*)(ws + A16_OFF), (const uint2*)(ws + CT16_OFF),
                       (const uint2*)(ws + W16_OFF), out);
}